// Round 2
// baseline (450.598 us; speedup 1.0000x reference)
//
#include <hip/hip_runtime.h>

#define TSTEPS 256
#define CHUNK  128   // t-steps per block: 1 chunk boundary -> only 8.4 MB halo re-read
#define GROUP  8     // t-steps per load/compute/store batch (8 loads in flight)

typedef float v4f __attribute__((ext_vector_type(4)));

__device__ __forceinline__ float4 f4mul(const float4 a, const float4 b) {
    return make_float4(a.x * b.x, a.y * b.y, a.z * b.z, a.w * b.w);
}
// 1 - a*b*m (b wave-uniform scalar) — NAND stage with delayed-n1 mask
__device__ __forceinline__ float4 f4nandm(const float4 a, const float b, const float4 m) {
    return make_float4(1.f - a.x * b * m.x, 1.f - a.y * b * m.y,
                       1.f - a.z * b * m.z, 1.f - a.w * b * m.w);
}

__global__ __launch_bounds__(256) void tanhP1_kernel(
    const float* __restrict__ x,
    const float* __restrict__ c2, const float* __restrict__ c3,
    const float* __restrict__ c4, const float* __restrict__ c5,
    float* __restrict__ out, int N4)
{
    // all 4 per-t constant bits in one float4 -> single broadcast ds_read_b128/step
    __shared__ float4 sbc[TSTEPS];
    const int tid = threadIdx.x;
    if (tid < TSTEPS)
        sbc[tid] = make_float4(c2[tid], c3[tid], c4[tid], c5[tid]);
    __syncthreads();

    const int j4 = blockIdx.x * blockDim.x + tid;   // float4 column index
    if (j4 >= N4) return;
    const int t0 = blockIdx.y * CHUNK;

    const float4* __restrict__ x4   = (const float4*)x + j4;
    float4* __restrict__       out4 = (float4*)out + j4;
    const size_t stride = (size_t)N4;

    float4 xd[8];  // xd[k] = x[t-1-k]
    float4 m[3];   // m[k]  = n1[t-1-k]

    if (t0 == 0) {
        #pragma unroll
        for (int k = 0; k < 8; ++k) xd[k] = make_float4(0.f, 0.f, 0.f, 0.f);
        #pragma unroll
        for (int k = 0; k < 3; ++k) m[k] = make_float4(0.f, 0.f, 0.f, 0.f);
    } else {
        // halo preload: t0 = 128 -> rows 120..127, all in range
        #pragma unroll
        for (int k = 0; k < 8; ++k)
            xd[k] = x4[(size_t)(t0 - 1 - k) * stride];
        #pragma unroll
        for (int k = 0; k < 3; ++k)
            m[k] = f4mul(xd[k], xd[k + 4]);   // n1[t0-1-k] = x[t0-1-k]*x[t0-5-k]
    }

    #pragma unroll 1
    for (int g = 0; g < CHUNK; g += GROUP) {
        const size_t base = (size_t)(t0 + g) * stride;

        // batch loads: 8 independent global_load_dwordx4 in flight
        float4 xt[GROUP];
        #pragma unroll
        for (int i = 0; i < GROUP; ++i)
            xt[i] = x4[base + (size_t)i * stride];

        float4 o[GROUP];
        #pragma unroll
        for (int i = 0; i < GROUP; ++i) {
            const float4 c = sbc[t0 + g + i];
            const float4 n1 = f4mul(xt[i], xd[3]);                 // x[t] & x[t-4]
            const float4 n2 = make_float4(1.f - n1.x * c.x, 1.f - n1.y * c.x,
                                          1.f - n1.z * c.x, 1.f - n1.w * c.x);
            const float4 n3 = f4nandm(n2, c.y, m[0]);
            const float4 n4 = f4nandm(n3, c.z, m[1]);
            const float4 n5 = f4nandm(n4, c.w, m[2]);
            o[i] = f4mul(n5, xd[7]);                               // n5 & x[t-8]

            // shift delay lines (renamed away by full unroll within the group)
            xd[7] = xd[6]; xd[6] = xd[5]; xd[5] = xd[4]; xd[4] = xd[3];
            xd[3] = xd[2]; xd[2] = xd[1]; xd[1] = xd[0]; xd[0] = xt[i];
            m[2] = m[1]; m[1] = m[0]; m[0] = n1;
        }

        // batch non-temporal stores: out is write-once, keep it out of L2
        #pragma unroll
        for (int i = 0; i < GROUP; ++i)
            __builtin_nontemporal_store(*(const v4f*)&o[i],
                                        (v4f*)&out4[base + (size_t)i * stride]);
    }
}

extern "C" void kernel_launch(void* const* d_in, const int* in_sizes, int n_in,
                              void* d_out, int out_size, void* d_ws, size_t ws_size,
                              hipStream_t stream) {
    const float* x  = (const float*)d_in[0];
    const float* c2 = (const float*)d_in[1];
    const float* c3 = (const float*)d_in[2];
    const float* c4 = (const float*)d_in[3];
    const float* c5 = (const float*)d_in[4];
    float* out = (float*)d_out;

    const int N  = in_sizes[0] / TSTEPS;  // 262144
    const int N4 = N / 4;                 // 65536 float4 columns

    dim3 block(256);
    dim3 grid((N4 + 255) / 256, TSTEPS / CHUNK);  // 256 x 2 = 512 blocks
    tanhP1_kernel<<<grid, block, 0, stream>>>(x, c2, c3, c4, c5, out, N4);
}

// Round 3
// 437.892 us; speedup vs baseline: 1.0290x; 1.0290x over previous
//
#include <hip/hip_runtime.h>

#define TSTEPS 256
#define CHUNK  64    // t-steps per block: 1024 blocks = 4/CU (R0-measured best balance)
#define GROUP  8     // t-steps per pipelined load/compute batch

__device__ __forceinline__ float4 f4mul(const float4 a, const float4 b) {
    return make_float4(a.x * b.x, a.y * b.y, a.z * b.z, a.w * b.w);
}
// 1 - a*b*m (b wave-uniform scalar) — NAND stage with delayed-n1 mask
__device__ __forceinline__ float4 f4nandm(const float4 a, const float b, const float4 m) {
    return make_float4(1.f - a.x * b * m.x, 1.f - a.y * b * m.y,
                       1.f - a.z * b * m.z, 1.f - a.w * b * m.w);
}

__global__ __launch_bounds__(256) void tanhP1_kernel(
    const float* __restrict__ x,
    const float* __restrict__ c2, const float* __restrict__ c3,
    const float* __restrict__ c4, const float* __restrict__ c5,
    float* __restrict__ out, int N4)
{
    // all 4 per-t constant bits in one float4 -> one broadcast ds_read_b128/step
    __shared__ float4 sbc[TSTEPS];
    const int tid = threadIdx.x;
    if (tid < TSTEPS)
        sbc[tid] = make_float4(c2[tid], c3[tid], c4[tid], c5[tid]);
    __syncthreads();

    const int j4 = blockIdx.x * blockDim.x + tid;   // float4 column index
    if (j4 >= N4) return;
    const int t0 = blockIdx.y * CHUNK;

    const float4* __restrict__ x4   = (const float4*)x + j4;
    float4* __restrict__       out4 = (float4*)out + j4;
    const size_t stride = (size_t)N4;

    float4 xd[8];  // xd[k] = x[t-1-k]
    float4 m[3];   // m[k]  = n1[t-1-k]

    if (t0 == 0) {
        #pragma unroll
        for (int k = 0; k < 8; ++k) xd[k] = make_float4(0.f, 0.f, 0.f, 0.f);
        #pragma unroll
        for (int k = 0; k < 3; ++k) m[k] = make_float4(0.f, 0.f, 0.f, 0.f);
    } else {
        // halo preload: t0 >= 64 -> all rows in range
        #pragma unroll
        for (int k = 0; k < 8; ++k)
            xd[k] = x4[(size_t)(t0 - 1 - k) * stride];
        #pragma unroll
        for (int k = 0; k < 3; ++k)
            m[k] = f4mul(xd[k], xd[k + 4]);   // n1[t0-1-k] = x[t0-1-k]*x[t0-5-k]
    }

    // one group: consume 8 prefetched rows, store 8 output rows immediately
    auto compute_group = [&](const float4 (&xt)[GROUP], int tg) {
        #pragma unroll
        for (int i = 0; i < GROUP; ++i) {
            const float4 c  = sbc[tg + i];
            const float4 n1 = f4mul(xt[i], xd[3]);                 // x[t] & x[t-4]
            const float4 n2 = make_float4(1.f - n1.x * c.x, 1.f - n1.y * c.x,
                                          1.f - n1.z * c.x, 1.f - n1.w * c.x);
            const float4 n3 = f4nandm(n2, c.y, m[0]);
            const float4 n4 = f4nandm(n3, c.z, m[1]);
            const float4 n5 = f4nandm(n4, c.w, m[2]);
            out4[(size_t)(tg + i) * stride] = f4mul(n5, xd[7]);    // n5 & x[t-8]

            xd[7] = xd[6]; xd[6] = xd[5]; xd[5] = xd[4]; xd[4] = xd[3];
            xd[3] = xd[2]; xd[2] = xd[1]; xd[1] = xd[0]; xd[0] = xt[i];
            m[2] = m[1]; m[1] = m[0]; m[0] = n1;
        }
    };

    float4 bufA[GROUP], bufB[GROUP];

    // prime the pipeline: group 0 loads in flight
    #pragma unroll
    for (int i = 0; i < GROUP; ++i)
        bufA[i] = x4[(size_t)(t0 + i) * stride];

    #pragma unroll 1
    for (int g = 0; g < CHUNK; g += 2 * GROUP) {
        // prefetch group g+1 while group g's loads complete / compute runs
        {
            const int tp = t0 + g + GROUP;           // < t0+CHUNK, always valid
            #pragma unroll
            for (int i = 0; i < GROUP; ++i)
                bufB[i] = x4[(size_t)(tp + i) * stride];
        }
        compute_group(bufA, t0 + g);

        // prefetch group g+2 (skip on the last pair — stay inside this chunk)
        if (g + 2 * GROUP < CHUNK) {
            const int tp = t0 + g + 2 * GROUP;
            #pragma unroll
            for (int i = 0; i < GROUP; ++i)
                bufA[i] = x4[(size_t)(tp + i) * stride];
        }
        compute_group(bufB, t0 + g + GROUP);
    }
}

extern "C" void kernel_launch(void* const* d_in, const int* in_sizes, int n_in,
                              void* d_out, int out_size, void* d_ws, size_t ws_size,
                              hipStream_t stream) {
    const float* x  = (const float*)d_in[0];
    const float* c2 = (const float*)d_in[1];
    const float* c3 = (const float*)d_in[2];
    const float* c4 = (const float*)d_in[3];
    const float* c5 = (const float*)d_in[4];
    float* out = (float*)d_out;

    const int N  = in_sizes[0] / TSTEPS;  // 262144
    const int N4 = N / 4;                 // 65536 float4 columns

    dim3 block(256);
    dim3 grid((N4 + 255) / 256, TSTEPS / CHUNK);  // 256 x 4 = 1024 blocks
    tanhP1_kernel<<<grid, block, 0, stream>>>(x, c2, c3, c4, c5, out, N4);
}

// Round 4
// 433.768 us; speedup vs baseline: 1.0388x; 1.0095x over previous
//
#include <hip/hip_runtime.h>

#define TSTEPS 256
#define CHUNK  64    // 1024 blocks = 4/CU (measured best balance)
#define GROUP  8     // t-steps per pipelined load/compute batch

typedef float v4f __attribute__((ext_vector_type(4)));

__device__ __forceinline__ float4 f4mul(const float4 a, const float4 b) {
    return make_float4(a.x * b.x, a.y * b.y, a.z * b.z, a.w * b.w);
}
// 1 - a*b*m (b wave-uniform scalar) — NAND stage with delayed-n1 mask
__device__ __forceinline__ float4 f4nandm(const float4 a, const float b, const float4 m) {
    return make_float4(1.f - a.x * b * m.x, 1.f - a.y * b * m.y,
                       1.f - a.z * b * m.z, 1.f - a.w * b * m.w);
}

// non-temporal float4 load/store: use-once streams, don't allocate in L2/LLC
__device__ __forceinline__ float4 ntload4(const float4* p) {
    v4f v = __builtin_nontemporal_load((const v4f*)p);
    return make_float4(v.x, v.y, v.z, v.w);
}
__device__ __forceinline__ void ntstore4(float4* p, const float4 v) {
    v4f t = {v.x, v.y, v.z, v.w};
    __builtin_nontemporal_store(t, (v4f*)p);
}

__global__ __launch_bounds__(256) void tanhP1_kernel(
    const float* __restrict__ x,
    const float* __restrict__ c2, const float* __restrict__ c3,
    const float* __restrict__ c4, const float* __restrict__ c5,
    float* __restrict__ out, int N4)
{
    // all 4 per-t constant bits in one float4 -> one broadcast ds_read_b128/step
    __shared__ float4 sbc[TSTEPS];
    const int tid = threadIdx.x;
    if (tid < TSTEPS)
        sbc[tid] = make_float4(c2[tid], c3[tid], c4[tid], c5[tid]);
    __syncthreads();

    const int j4 = blockIdx.x * blockDim.x + tid;   // float4 column index
    if (j4 >= N4) return;
    const int t0 = blockIdx.y * CHUNK;

    const float4* __restrict__ x4   = (const float4*)x + j4;
    float4* __restrict__       out4 = (float4*)out + j4;
    const size_t stride = (size_t)N4;

    float4 xd[8];  // xd[k] = x[t-1-k]
    float4 m[3];   // m[k]  = n1[t-1-k]

    if (t0 == 0) {
        #pragma unroll
        for (int k = 0; k < 8; ++k) xd[k] = make_float4(0.f, 0.f, 0.f, 0.f);
        #pragma unroll
        for (int k = 0; k < 3; ++k) m[k] = make_float4(0.f, 0.f, 0.f, 0.f);
    } else {
        // halo preload (re-read rows are the one reuse: leave them cacheable)
        #pragma unroll
        for (int k = 0; k < 8; ++k)
            xd[k] = x4[(size_t)(t0 - 1 - k) * stride];
        #pragma unroll
        for (int k = 0; k < 3; ++k)
            m[k] = f4mul(xd[k], xd[k + 4]);   // n1[t0-1-k] = x[t0-1-k]*x[t0-5-k]
    }

    // one group: consume 8 prefetched rows, store 8 output rows (nt)
    auto compute_group = [&](const float4 (&xt)[GROUP], int tg) {
        #pragma unroll
        for (int i = 0; i < GROUP; ++i) {
            const float4 c  = sbc[tg + i];
            const float4 n1 = f4mul(xt[i], xd[3]);                 // x[t] & x[t-4]
            const float4 n2 = make_float4(1.f - n1.x * c.x, 1.f - n1.y * c.x,
                                          1.f - n1.z * c.x, 1.f - n1.w * c.x);
            const float4 n3 = f4nandm(n2, c.y, m[0]);
            const float4 n4 = f4nandm(n3, c.z, m[1]);
            const float4 n5 = f4nandm(n4, c.w, m[2]);
            ntstore4(&out4[(size_t)(tg + i) * stride], f4mul(n5, xd[7]));

            xd[7] = xd[6]; xd[6] = xd[5]; xd[5] = xd[4]; xd[4] = xd[3];
            xd[3] = xd[2]; xd[2] = xd[1]; xd[1] = xd[0]; xd[0] = xt[i];
            m[2] = m[1]; m[1] = m[0]; m[0] = n1;
        }
    };

    float4 bufA[GROUP], bufB[GROUP];

    // prime the pipeline: group 0 loads in flight
    #pragma unroll
    for (int i = 0; i < GROUP; ++i)
        bufA[i] = ntload4(&x4[(size_t)(t0 + i) * stride]);

    #pragma unroll 1
    for (int g = 0; g < CHUNK; g += 2 * GROUP) {
        // prefetch group g+1 while group g's loads complete / compute runs
        {
            const int tp = t0 + g + GROUP;           // < t0+CHUNK, always valid
            #pragma unroll
            for (int i = 0; i < GROUP; ++i)
                bufB[i] = ntload4(&x4[(size_t)(tp + i) * stride]);
        }
        compute_group(bufA, t0 + g);

        // prefetch group g+2 (skip on the last pair — stay inside this chunk)
        if (g + 2 * GROUP < CHUNK) {
            const int tp = t0 + g + 2 * GROUP;
            #pragma unroll
            for (int i = 0; i < GROUP; ++i)
                bufA[i] = ntload4(&x4[(size_t)(tp + i) * stride]);
        }
        compute_group(bufB, t0 + g + GROUP);
    }
}

extern "C" void kernel_launch(void* const* d_in, const int* in_sizes, int n_in,
                              void* d_out, int out_size, void* d_ws, size_t ws_size,
                              hipStream_t stream) {
    const float* x  = (const float*)d_in[0];
    const float* c2 = (const float*)d_in[1];
    const float* c3 = (const float*)d_in[2];
    const float* c4 = (const float*)d_in[3];
    const float* c5 = (const float*)d_in[4];
    float* out = (float*)d_out;

    const int N  = in_sizes[0] / TSTEPS;  // 262144
    const int N4 = N / 4;                 // 65536 float4 columns

    dim3 block(256);
    dim3 grid((N4 + 255) / 256, TSTEPS / CHUNK);  // 256 x 4 = 1024 blocks
    tanhP1_kernel<<<grid, block, 0, stream>>>(x, c2, c3, c4, c5, out, N4);
}

// Round 5
// 424.676 us; speedup vs baseline: 1.0610x; 1.0214x over previous
//
#include <hip/hip_runtime.h>

#define TSTEPS 256
#define GROUP  8     // t-steps per pipelined load/compute batch

typedef float v4f __attribute__((ext_vector_type(4)));

__device__ __forceinline__ float4 f4mul(const float4 a, const float4 b) {
    return make_float4(a.x * b.x, a.y * b.y, a.z * b.z, a.w * b.w);
}
// 1 - a*b*m (b wave-uniform scalar) — NAND stage with delayed-n1 mask
__device__ __forceinline__ float4 f4nandm(const float4 a, const float b, const float4 m) {
    return make_float4(1.f - a.x * b * m.x, 1.f - a.y * b * m.y,
                       1.f - a.z * b * m.z, 1.f - a.w * b * m.w);
}

// non-temporal float4 load/store: use-once streams, don't allocate in L2/LLC
__device__ __forceinline__ float4 ntload4(const float4* p) {
    v4f v = __builtin_nontemporal_load((const v4f*)p);
    return make_float4(v.x, v.y, v.z, v.w);
}
__device__ __forceinline__ void ntstore4(float4* p, const float4 v) {
    v4f t = {v.x, v.y, v.z, v.w};
    __builtin_nontemporal_store(t, (v4f*)p);
}

// Full-T sweep per block: 256 blocks (1/CU), ZERO halo re-read, and every CU
// walks the t-rows in lockstep -> the whole GPU streams one contiguous row
// front at a time (best DRAM row/channel locality).
__global__ __launch_bounds__(256) void tanhP1_kernel(
    const float* __restrict__ x,
    const float* __restrict__ c2, const float* __restrict__ c3,
    const float* __restrict__ c4, const float* __restrict__ c5,
    float* __restrict__ out, int N4)
{
    // all 4 per-t constant bits in one float4 -> one broadcast ds_read_b128/step
    __shared__ float4 sbc[TSTEPS];
    const int tid = threadIdx.x;
    if (tid < TSTEPS)
        sbc[tid] = make_float4(c2[tid], c3[tid], c4[tid], c5[tid]);
    __syncthreads();

    const int j4 = blockIdx.x * blockDim.x + tid;   // float4 column index
    if (j4 >= N4) return;

    const float4* __restrict__ x4   = (const float4*)x + j4;
    float4* __restrict__       out4 = (float4*)out + j4;
    const size_t stride = (size_t)N4;

    // zero-initialized carry (t starts at 0 for every block)
    float4 xd[8];  // xd[k] = x[t-1-k]
    float4 m[3];   // m[k]  = n1[t-1-k]
    #pragma unroll
    for (int k = 0; k < 8; ++k) xd[k] = make_float4(0.f, 0.f, 0.f, 0.f);
    #pragma unroll
    for (int k = 0; k < 3; ++k) m[k] = make_float4(0.f, 0.f, 0.f, 0.f);

    // one group: consume 8 prefetched rows, store 8 output rows (nt)
    auto compute_group = [&](const float4 (&xt)[GROUP], int tg) {
        #pragma unroll
        for (int i = 0; i < GROUP; ++i) {
            const float4 c  = sbc[tg + i];
            const float4 n1 = f4mul(xt[i], xd[3]);                 // x[t] & x[t-4]
            const float4 n2 = make_float4(1.f - n1.x * c.x, 1.f - n1.y * c.x,
                                          1.f - n1.z * c.x, 1.f - n1.w * c.x);
            const float4 n3 = f4nandm(n2, c.y, m[0]);
            const float4 n4 = f4nandm(n3, c.z, m[1]);
            const float4 n5 = f4nandm(n4, c.w, m[2]);
            ntstore4(&out4[(size_t)(tg + i) * stride], f4mul(n5, xd[7]));

            xd[7] = xd[6]; xd[6] = xd[5]; xd[5] = xd[4]; xd[4] = xd[3];
            xd[3] = xd[2]; xd[2] = xd[1]; xd[1] = xd[0]; xd[0] = xt[i];
            m[2] = m[1]; m[1] = m[0]; m[0] = n1;
        }
    };

    float4 bufA[GROUP], bufB[GROUP];

    // prime the pipeline: group 0 loads in flight
    #pragma unroll
    for (int i = 0; i < GROUP; ++i)
        bufA[i] = ntload4(&x4[(size_t)i * stride]);

    #pragma unroll 1
    for (int g = 0; g < TSTEPS; g += 2 * GROUP) {
        // prefetch group g+1 while group g's loads complete / compute runs
        {
            const int tp = g + GROUP;                // < TSTEPS, always valid
            #pragma unroll
            for (int i = 0; i < GROUP; ++i)
                bufB[i] = ntload4(&x4[(size_t)(tp + i) * stride]);
        }
        compute_group(bufA, g);

        // prefetch group g+2 (skip past the end)
        if (g + 2 * GROUP < TSTEPS) {
            const int tp = g + 2 * GROUP;
            #pragma unroll
            for (int i = 0; i < GROUP; ++i)
                bufA[i] = ntload4(&x4[(size_t)(tp + i) * stride]);
        }
        compute_group(bufB, g + GROUP);
    }
}

extern "C" void kernel_launch(void* const* d_in, const int* in_sizes, int n_in,
                              void* d_out, int out_size, void* d_ws, size_t ws_size,
                              hipStream_t stream) {
    const float* x  = (const float*)d_in[0];
    const float* c2 = (const float*)d_in[1];
    const float* c3 = (const float*)d_in[2];
    const float* c4 = (const float*)d_in[3];
    const float* c5 = (const float*)d_in[4];
    float* out = (float*)d_out;

    const int N  = in_sizes[0] / TSTEPS;  // 262144
    const int N4 = N / 4;                 // 65536 float4 columns

    dim3 block(256);
    dim3 grid(N4 / 256, 1);               // 256 blocks = 1 per CU, full-T sweep
    tanhP1_kernel<<<grid, block, 0, stream>>>(x, c2, c3, c4, c5, out, N4);
}